// Round 4
// baseline (246.054 us; speedup 1.0000x reference)
//
#include <hip/hip_runtime.h>

// EMA recurrence: s_t = alpha*s_{t-1} + (1-alpha)*x_t
// x: (T=1024, 32, 1024) fp32, state: (32, 1024) fp32
// out = concat(all states (T,32,1024), final_state (32,1024))
//
// R3: R2 showed dur pinned at 93us across occupancy 17->31% with VGPR=20:
// latency-bound, one load-group in flight per wave. Fix: float4 lanes
// (16B/lane) + explicit 2-stage register pipeline (prefetch next group of 8
// while consuming current) so >=8 float4 loads (8KB/wave) stay in flight
// continuously. WARM 96->64 (alpha^64 ~ 1.2e-3 splice, threshold 7.8e-2).
// Warm-up re-reads are L3-absorbed (R2: FETCH ~= size of x), so the only
// real HBM traffic is x once (134MB) + out (131MB).

typedef float f4 __attribute__((ext_vector_type(4)));

constexpr int T = 1024;
constexpr int C = 32 * 1024;       // channels per timestep (contiguous)
constexpr int V = 4;
constexpr int CV = C / V;          // 8192 float4 channels
constexpr int CHUNK = 64;          // timesteps per chunk
constexpr int NCHUNK = T / CHUNK;  // 16
constexpr int WARM = 64;           // warm-up steps (clamped at t=0)
constexpr int U = 8;               // pipeline group size

template<int STEPS, bool STORE>
__device__ __forceinline__ void run_steps(const f4* __restrict__ xp,
                                          f4* __restrict__ op,
                                          f4& s) {
    constexpr int NG = STEPS / U;
    const float a = 0.9f;
    const float oma = 0.1f;

    f4 cur[U];
    #pragma unroll
    for (int i = 0; i < U; ++i) cur[i] = xp[(size_t)i * CV];

    #pragma unroll
    for (int g = 0; g < NG; ++g) {
        f4 nxt[U];
        if (g + 1 < NG) {
            #pragma unroll
            for (int i = 0; i < U; ++i)
                nxt[i] = xp[(size_t)((g + 1) * U + i) * CV];
        }
        #pragma unroll
        for (int i = 0; i < U; ++i) {
            s = s * a + cur[i] * oma;
            if (STORE)
                __builtin_nontemporal_store(s, op + (size_t)(g * U + i) * CV);
        }
        if (g + 1 < NG) {
            #pragma unroll
            for (int i = 0; i < U; ++i) cur[i] = nxt[i];
        }
    }
}

__global__ __launch_bounds__(256)
void ExponentialDecay_23708219474744_kernel(const float* __restrict__ x,
                                            const float* __restrict__ state,
                                            float* __restrict__ out) {
    const int cv = blockIdx.x * blockDim.x + threadIdx.x;   // 0..CV-1, coalesced
    const int chunk = blockIdx.y;
    const int t0 = chunk * CHUNK;

    const f4* xv = (const f4*)x;
    f4* ov = (f4*)out;

    int tw = t0 - WARM;
    f4 s;
    if (tw <= 0) {
        tw = 0;
        s = ((const f4*)state)[cv];   // exact initial state (chunks 0 and 1)
    } else {
        s = (f4)0.0f;                 // alpha^WARM splice error
    }

    // warm-up: recurrence only, no stores. Trip count is 0 (chunk 0) or
    // WARM==CHUNK (chunks >= 1) — wave-uniform static loops.
    if (chunk > 0) {
        run_steps<WARM, false>(xv + (size_t)tw * CV + cv, nullptr, s);
    }

    // main: recurrence + nontemporal stores
    run_steps<CHUNK, true>(xv + (size_t)t0 * CV + cv,
                           ov + (size_t)t0 * CV + cv, s);

    if (chunk == NCHUNK - 1) {
        // final_state, appended after the (T,32,1024) outputs
        ov[(size_t)T * CV + cv] = s;
    }
}

extern "C" void kernel_launch(void* const* d_in, const int* in_sizes, int n_in,
                              void* d_out, int out_size, void* d_ws, size_t ws_size,
                              hipStream_t stream) {
    const float* x = (const float*)d_in[0];
    const float* state = (const float*)d_in[1];
    float* out = (float*)d_out;

    dim3 block(256);
    dim3 grid(CV / 256, NCHUNK);   // 32 x 16 = 512 blocks = 2 per CU
    ExponentialDecay_23708219474744_kernel<<<grid, block, 0, stream>>>(x, state, out);
}